// Round 10
// baseline (297.135 us; speedup 1.0000x reference)
//
#include <hip/hip_runtime.h>

// Problem dims (hardcoded from reference)
#define T_STEPS 100
#define B_N     128
#define IN_F    512
#define OUT_F   512

// fp64 decay constants: exp(-DT/TAU_*)
#define ALPHA_D 0.8187307530779818   // exp(-1/5)   synaptic
#define BETA_D  0.9512294245007140   // exp(-1/20)  membrane

typedef __attribute__((ext_vector_type(8))) short bf16x8;
typedef __attribute__((ext_vector_type(4))) float f32x4;

static __device__ __forceinline__ unsigned int f2bf(float f) {
    union { float f; unsigned int u; } v; v.f = f;
    return (v.u + 0x7FFFu + ((v.u >> 16) & 1u)) >> 16;   // RNE
}

// ---------------------------------------------------------------------------
// K1: transpose W (OUT x IN) -> Wt (IN x OUT).  (1 MB of ws)
// ---------------------------------------------------------------------------
__global__ __launch_bounds__(256) void transposeW(const float* __restrict__ W,
                                                  float* __restrict__ Wt) {
    __shared__ float tile[32][33];
    const int bx = blockIdx.x & 15;   // i-tile
    const int by = blockIdx.x >> 4;   // o-tile
    const int tx = threadIdx.x & 31;
    const int ty = threadIdx.x >> 5;  // 0..7
#pragma unroll
    for (int k = 0; k < 32; k += 8) {
        int o = by * 32 + ty + k;
        tile[ty + k][tx] = W[o * IN_F + bx * 32 + tx];
    }
    __syncthreads();
#pragma unroll
    for (int k = 0; k < 32; k += 8) {
        int i = bx * 32 + ty + k;
        Wt[i * OUT_F + by * 32 + tx] = tile[tx][ty + k];
    }
}

// ---------------------------------------------------------------------------
// K2: per-(t,b) ascending active-index lists, LO/HI SPLIT byte encoding:
// list entry = i & 255; entries at position < cnt_lo have i < 256 (j<4),
// the rest have i >= 256. Count pair packed: Cg = cnt_lo | (cnt_total<<16).
// (Fixes R9's fatal byte truncation of i in [256,512).)
// One wave per (t,b); 4 pairs per block -> 3200 blocks.
// ---------------------------------------------------------------------------
__global__ __launch_bounds__(256) void prep_lists(const float* __restrict__ x,
                                                  unsigned char* __restrict__ Lg,
                                                  int* __restrict__ Cg) {
    const int pair = blockIdx.x * 4 + (threadIdx.x >> 6);  // 0..12799 == t*128+b
    const int lane = threadIdx.x & 63;
    const int t = pair >> 7, b = pair & 127;
    const float* xr = x + (size_t)pair * IN_F;
    unsigned char* lrow = Lg + (size_t)b * (128 * 128) + t * 128;
    int base = 0, clo = 0;
#pragma unroll
    for (int j = 0; j < 8; ++j) {
        const float v = xr[j * 64 + lane];
        const unsigned long long m = __ballot(v > 0.5f);
        if (v > 0.5f) {
            const int pos = base + __popcll(m & ((1ull << lane) - 1ull));
            lrow[pos] = (unsigned char)((j * 64 + lane) & 255);
        }
        base += __popcll(m);
        if (j == 3) clo = base;
    }
    if (lane == 0) Cg[b * 128 + t] = clo | (base << 16);
}

// ---------------------------------------------------------------------------
// K3: FUSED LIF + trace. One block per (b, o-chunk of 256): 256 blocks.
// Phase A: t-loop; C gathered in fp64 from L2-resident Wt via LDS lists
//   (4 partial chains -> 4+ loads in flight; fixed combine order, determin-
//   istic; fp64 => no spike flips vs f64 ref); LIF recurrence in registers;
//   S/Uh via nontemporal stores; P stashed into LDS in MFMA-swizzled bf16.
// Phase B: P fragments hoisted to regs once; 8 X-tiles staged inline from
//   f32 x; 16x16x32 bf16 MFMA; nt stores.
// ws needed: Wt 1MB + lists 2MB + counts 64KB = 3.2 MB (launch-proven R9).
// ---------------------------------------------------------------------------
__global__ __launch_bounds__(256) void fused_lif_trace(const float* __restrict__ x,
                                                       const float* __restrict__ Wt,
                                                       const unsigned char* __restrict__ Lg,
                                                       const int* __restrict__ Cg,
                                                       float* __restrict__ S_out,
                                                       float* __restrict__ Uh,
                                                       float* __restrict__ trace) {
    __shared__ char smem[98816];
    char* const Psm = smem;                     // [256 o][256B k] bf16 swz, 64 KB
    char* const Lsm = smem + 65536;             // [128 t][128] bytes, 16 KB
    int*  const Csm = (int*)(smem + 81920);     // [128] count pairs
    char* const Xsm = smem + 82432;             // [64 i][256B k] bf16 swz, 16 KB

    const int tid = threadIdx.x;
    const int b   = blockIdx.x & 127;           // bid%8 == b%8 -> XCD locality
    const int ob  = blockIdx.x >> 7;            // o-chunk 0/1

    // ---- init: zero P (covers k=100..127 pad), copy lists + counts ----
    {
        const uint4 z = make_uint4(0u, 0u, 0u, 0u);
#pragma unroll
        for (int r = 0; r < 16; ++r) ((uint4*)Psm)[tid + r * 256] = z;
        const uint4* Lg4 = (const uint4*)(Lg + (size_t)b * (128 * 128));
#pragma unroll
        for (int r = 0; r < 4; ++r) ((uint4*)Lsm)[tid + r * 256] = Lg4[tid + r * 256];
        if (tid < 128) Csm[tid] = Cg[b * 128 + tid];
    }
    __syncthreads();

    // ---- phase A: LIF scan (no block barriers inside) ----
    {
        const int og = ob * 256 + tid;
        const float* const Wlo = Wt + og;                    // i in [0,256)
        const float* const Whi = Wt + (size_t)256 * OUT_F + og;  // i in [256,512)
        const size_t N = (size_t)B_N * OUT_F;
        const size_t base = (size_t)b * OUT_F + og;
        double I = 0.0, U = 0.0;
        for (int t = 0; t < T_STEPS; ++t) {
            const int cp   = Csm[t];
            const int clo  = cp & 0xFFFF;
            const int ctot = cp >> 16;
            const unsigned char* lp = (const unsigned char*)Lsm + t * 128;

            double c0 = 0.0, c1 = 0.0, c2 = 0.0, c3 = 0.0;
            int k = 0;
            for (; k + 3 < clo; k += 4) {       // 4 independent chains
                c0 += (double)Wlo[(size_t)lp[k]     * OUT_F];
                c1 += (double)Wlo[(size_t)lp[k + 1] * OUT_F];
                c2 += (double)Wlo[(size_t)lp[k + 2] * OUT_F];
                c3 += (double)Wlo[(size_t)lp[k + 3] * OUT_F];
            }
            for (; k < clo; ++k) c0 += (double)Wlo[(size_t)lp[k] * OUT_F];
            for (; k + 3 < ctot; k += 4) {
                c0 += (double)Whi[(size_t)lp[k]     * OUT_F];
                c1 += (double)Whi[(size_t)lp[k + 1] * OUT_F];
                c2 += (double)Whi[(size_t)lp[k + 2] * OUT_F];
                c3 += (double)Whi[(size_t)lp[k + 3] * OUT_F];
            }
            for (; k < ctot; ++k) c0 += (double)Whi[(size_t)lp[k] * OUT_F];
            const double c = (c0 + c2) + (c1 + c3);          // fixed order

            I = ALPHA_D * I + c;
            U = BETA_D * U + I;
            const double Sv = (U >= 1.0) ? 1.0 : 0.0;
            __builtin_nontemporal_store((float)Sv, S_out + (size_t)t * N + base);
            __builtin_nontemporal_store((float)U,  Uh + (size_t)(2 * t) * N + base);     // U_pre
            U -= Sv;
            __builtin_nontemporal_store((float)U,  Uh + (size_t)(2 * t + 1) * N + base); // U_post
            {
                const float du = fabsf((float)U - 1.0f);
                const float dd = 1.0f + 0.03f * du;
                const float pv = __expf(-0.05f * (float)(T_STEPS - 1 - t)) / (dd * dd);
                *(unsigned short*)(Psm + (((unsigned)(tid * 256 + 2 * t)) ^
                                          (((unsigned)(tid & 7)) << 4))) = (unsigned short)f2bf(pv);
            }
            U -= Sv;                                         // second reset (as in source)
        }
    }
    __syncthreads();

    // ---- phase B: trace = P^T @ X ----
    const int w = tid >> 6, l = tid & 63, lo16 = l & 15, g4 = l >> 4;

    bf16x8 af[4][4];   // P fragments, hoisted once (wave w owns o rows [w*64, w*64+64))
#pragma unroll
    for (int m = 0; m < 4; ++m) {
        const int row = w * 64 + m * 16 + lo16;
#pragma unroll
        for (int kk = 0; kk < 4; ++kk) {
            const unsigned off = (unsigned)(row * 256 + kk * 64 + g4 * 16)
                                 ^ ((unsigned)(row & 7) << 4);
            af[m][kk] = *(const bf16x8*)(Psm + off);
        }
    }

    float* const tb = trace + (size_t)b * (OUT_F * IN_F);

    for (int it = 0; it < 8; ++it) {
        // stage X tile [64 i][128 k] bf16 swizzled, inline f32->bf16 (binary: exact)
#pragma unroll
        for (int r = 0; r < 4; ++r) {
            const int g  = tid + r * 256;     // 1024 = 64 i x 16 kg
            const int i  = g & 63;
            const int kg = g >> 6;
            unsigned int h[4];
#pragma unroll
            for (int jj = 0; jj < 4; ++jj) {
                const int t0 = kg * 8 + jj * 2, t1 = t0 + 1;
                float v0 = 0.f, v1 = 0.f;
                if (t0 < T_STEPS) v0 = x[(size_t)t0 * (B_N * IN_F) + b * IN_F + it * 64 + i];
                if (t1 < T_STEPS) v1 = x[(size_t)t1 * (B_N * IN_F) + b * IN_F + it * 64 + i];
                h[jj] = f2bf(v0) | (f2bf(v1) << 16);
            }
            const unsigned loff = (unsigned)(i * 256) +
                (((unsigned)(kg * 16)) ^ (((unsigned)(i & 7)) << 4));
            *(uint4*)(Xsm + loff) = make_uint4(h[0], h[1], h[2], h[3]);
        }
        __syncthreads();

        f32x4 acc[4][4];
#pragma unroll
        for (int m = 0; m < 4; ++m)
#pragma unroll
            for (int n = 0; n < 4; ++n) acc[m][n] = (f32x4){0.f, 0.f, 0.f, 0.f};

#pragma unroll
        for (int kk = 0; kk < 4; ++kk) {
            bf16x8 bfr[4];
#pragma unroll
            for (int n = 0; n < 4; ++n) {
                const int row = n * 16 + lo16;
                const unsigned off = (unsigned)(row * 256 + kk * 64 + g4 * 16)
                                     ^ ((unsigned)(row & 7) << 4);
                bfr[n] = *(const bf16x8*)(Xsm + off);
            }
#pragma unroll
            for (int m = 0; m < 4; ++m)
#pragma unroll
                for (int n = 0; n < 4; ++n)
                    acc[m][n] = __builtin_amdgcn_mfma_f32_16x16x32_bf16(af[m][kk], bfr[n], acc[m][n], 0, 0, 0);
        }

        // store 256(o) x 64(i) tile; D: col=lane&15 (i), row=(lane>>4)*4+reg (o)
#pragma unroll
        for (int m = 0; m < 4; ++m)
#pragma unroll
            for (int rr = 0; rr < 4; ++rr) {
                const int o = ob * 256 + w * 64 + m * 16 + g4 * 4 + rr;
#pragma unroll
                for (int n = 0; n < 4; ++n)
                    __builtin_nontemporal_store(acc[m][n][rr],
                        tb + (size_t)o * IN_F + it * 64 + n * 16 + lo16);
            }
        __syncthreads();
    }
}

// ---------------------------------------------------------------------------
// Fallback chain (ws < 3.2 MB): R4-proven kernels.
// ---------------------------------------------------------------------------
__global__ __launch_bounds__(256) void syn_current(const float* __restrict__ x,
                                                   const float* __restrict__ Wt,
                                                   double* __restrict__ C) {
    const int tb  = blockIdx.x;          // t*B + b
    const int tid = threadIdx.x;

    __shared__ int s_idx[IN_F];
    __shared__ int s_cnt;

    if (tid < 64) {
        const float* xr = x + (size_t)tb * IN_F;
        int base = 0;
#pragma unroll
        for (int j = 0; j < 8; ++j) {
            const float v = xr[j * 64 + tid];
            const unsigned long long m = __ballot(v > 0.5f);
            if (v > 0.5f) {
                const int pos = base + __popcll(m & ((1ull << tid) - 1ull));
                s_idx[pos] = j * 64 + tid;
            }
            base += __popcll(m);
        }
        if (tid == 0) s_cnt = base;
    }
    __syncthreads();

    const int cnt = s_cnt;
    double c0 = 0.0, c1 = 0.0;
    const float* W0 = Wt + tid;
    const float* W1 = Wt + tid + 256;
    for (int k = 0; k < cnt; ++k) {
        const int i = s_idx[k];
        c0 += (double)W0[(size_t)i * OUT_F];
        c1 += (double)W1[(size_t)i * OUT_F];
    }

    double* Cr = C + (size_t)tb * OUT_F;
    Cr[tid]       = c0;
    Cr[tid + 256] = c1;
}

#define LIF_STEP(BUF, J, CB)                                                   \
    {                                                                          \
        const int t = (CB) * 10 + (J);                                         \
        I = ALPHA_D * I + BUF[J];                                              \
        U = BETA_D * U + I;                                                    \
        const double Sv = (U >= 1.0) ? 1.0 : 0.0;                              \
        S_out[(size_t)t * N + pos] = (float)Sv;                                \
        Uh[(size_t)(2 * t) * N + pos] = (float)U;                              \
        U -= Sv;                                                               \
        Uh[(size_t)(2 * t + 1) * N + pos] = (float)U;                          \
        U -= Sv;                                                               \
    }

__global__ __launch_bounds__(256) void lif_pointwise(const double* __restrict__ C,
                                                     float* __restrict__ S_out,
                                                     float* __restrict__ Uh) {
    const int pos = blockIdx.x * 256 + threadIdx.x;
    const size_t N = (size_t)B_N * OUT_F;

    double I = 0.0, U = 0.0;
    double bufA[10], bufB[10];

#pragma unroll
    for (int j = 0; j < 10; ++j) bufA[j] = C[(size_t)j * N + pos];

    for (int cb = 0; cb < 10; cb += 2) {
#pragma unroll
        for (int j = 0; j < 10; ++j) bufB[j] = C[((size_t)(cb + 1) * 10 + j) * N + pos];
#pragma unroll
        for (int j = 0; j < 10; ++j) LIF_STEP(bufA, j, cb)
        if (cb + 2 < 10) {
#pragma unroll
            for (int j = 0; j < 10; ++j) bufA[j] = C[((size_t)(cb + 2) * 10 + j) * N + pos];
        }
#pragma unroll
        for (int j = 0; j < 10; ++j) LIF_STEP(bufB, j, cb + 1)
    }
}

__global__ __launch_bounds__(256) void trace_mfma(const float* __restrict__ x,
                                                  const float* __restrict__ Uh,
                                                  float* __restrict__ trace) {
    __shared__ unsigned short Pa[128 * 128];
    __shared__ unsigned short Xb[128 * 128];

    const int idx  = blockIdx.x;
    const int xcd  = idx & 7;
    const int slot = idx >> 3;
    const int b    = xcd * 16 + (slot >> 4);
    const int tile = slot & 15;
    const int ot   = tile >> 2;
    const int it   = tile & 3;
    const int tid  = threadIdx.x;

    char* const pbase = (char*)Pa;
    char* const xbase = (char*)Xb;

#pragma unroll
    for (int r = 0; r < 8; ++r) {
        const int g  = tid + r * 256;
        const int i  = g & 127;
        const int kg = g >> 7;
        unsigned int h[4];
#pragma unroll
        for (int jj = 0; jj < 4; ++jj) {
            const int t0 = kg * 8 + jj * 2, t1 = t0 + 1;
            float v0 = 0.f, v1 = 0.f;
            if (t0 < T_STEPS) v0 = x[(size_t)t0 * (B_N * IN_F) + b * IN_F + it * 128 + i];
            if (t1 < T_STEPS) v1 = x[(size_t)t1 * (B_N * IN_F) + b * IN_F + it * 128 + i];
            h[jj] = f2bf(v0) | (f2bf(v1) << 16);
        }
        unsigned int off = (unsigned int)(i * 256 + kg * 16) ^ ((unsigned int)(i & 7) << 4);
        *(uint4*)(xbase + off) = make_uint4(h[0], h[1], h[2], h[3]);
    }

#pragma unroll
    for (int r = 0; r < 8; ++r) {
        const int g  = tid + r * 256;
        const int o  = g & 127;
        const int kg = g >> 7;
        unsigned int h[4];
#pragma unroll
        for (int jj = 0; jj < 4; ++jj) {
            unsigned int hw[2];
#pragma unroll
            for (int e = 0; e < 2; ++e) {
                const int t = kg * 8 + jj * 2 + e;
                float p = 0.f;
                if (t < T_STEPS) {
                    const float u  = Uh[(size_t)(2 * t + 1) * (B_N * OUT_F) + b * OUT_F + ot * 128 + o];
                    const float du = fabsf(u - 1.0f);
                    const float d  = 1.0f + 0.03f * du;
                    const float gp = __expf(-0.05f * (float)(T_STEPS - 1 - t));
                    p = gp / (d * d);
                }
                hw[e] = f2bf(p);
            }
            h[jj] = hw[0] | (hw[1] << 16);
        }
        unsigned int off = (unsigned int)(o * 256 + kg * 16) ^ ((unsigned int)(o & 7) << 4);
        *(uint4*)(pbase + off) = make_uint4(h[0], h[1], h[2], h[3]);
    }
    __syncthreads();

    const int w    = tid >> 6;
    const int l    = tid & 63;
    const int wo   = (w >> 1) * 64;
    const int wi   = (w & 1) * 64;
    const int lo16 = l & 15;
    const int g4   = l >> 4;

    f32x4 acc[4][4];
#pragma unroll
    for (int m = 0; m < 4; ++m)
#pragma unroll
        for (int n = 0; n < 4; ++n) acc[m][n] = (f32x4){0.f, 0.f, 0.f, 0.f};

#pragma unroll
    for (int kk = 0; kk < 4; ++kk) {
        bf16x8 af[4], bfr[4];
#pragma unroll
        for (int m = 0; m < 4; ++m) {
            const int row = wo + m * 16 + lo16;
            const unsigned int off = (unsigned int)(row * 256 + kk * 64 + g4 * 16)
                                     ^ ((unsigned int)(row & 7) << 4);
            af[m] = *(const bf16x8*)(pbase + off);
        }
#pragma unroll
        for (int n = 0; n < 4; ++n) {
            const int row = wi + n * 16 + lo16;
            const unsigned int off = (unsigned int)(row * 256 + kk * 64 + g4 * 16)
                                     ^ ((unsigned int)(row & 7) << 4);
            bfr[n] = *(const bf16x8*)(xbase + off);
        }
#pragma unroll
        for (int m = 0; m < 4; ++m)
#pragma unroll
            for (int n = 0; n < 4; ++n)
                acc[m][n] = __builtin_amdgcn_mfma_f32_16x16x32_bf16(af[m], bfr[n], acc[m][n], 0, 0, 0);
    }

    float* tb = trace + (size_t)b * (OUT_F * IN_F);
#pragma unroll
    for (int m = 0; m < 4; ++m) {
#pragma unroll
        for (int rr = 0; rr < 4; ++rr) {
            const int o = ot * 128 + wo + m * 16 + g4 * 4 + rr;
#pragma unroll
            for (int n = 0; n < 4; ++n) {
                const int i = it * 128 + wi + n * 16 + lo16;
                tb[(size_t)o * IN_F + i] = acc[m][n][rr];
            }
        }
    }
}

// ---------------------------------------------------------------------------
extern "C" void kernel_launch(void* const* d_in, const int* in_sizes, int n_in,
                              void* d_out, int out_size, void* d_ws, size_t ws_size,
                              hipStream_t stream) {
    const float* x = (const float*)d_in[0];   // (T, B, IN) binary spikes
    const float* W = (const float*)d_in[1];   // (OUT, IN)

    float* out   = (float*)d_out;
    float* S_out = out;                                            // (T, B, OUT)
    float* Uh    = out + (size_t)T_STEPS * B_N * OUT_F;            // (2T, B, OUT)
    float* trace = Uh + (size_t)2 * T_STEPS * B_N * OUT_F;         // (B, OUT, IN)

    // ws layout: Wt (1 MB) | lists L[b][t][128] (2 MB) | counts (64 KB)
    const size_t WT_BYTES = (size_t)IN_F * OUT_F * 4;              // 1,048,576
    const size_t L_BYTES  = (size_t)128 * 128 * 128;               // 2,097,152
    const size_t C_BYTES  = (size_t)128 * 128 * 4;                 // 65,536
    const bool   ws_ok    = ws_size >= WT_BYTES + L_BYTES + C_BYTES;

    float*         Wt = (float*)d_ws;
    unsigned char* Lg = (unsigned char*)d_ws + WT_BYTES;
    int*           Cg = (int*)((char*)d_ws + WT_BYTES + L_BYTES);

    transposeW<<<256, 256, 0, stream>>>(W, Wt);
    if (ws_ok) {
        prep_lists<<<3200, 256, 0, stream>>>(x, Lg, Cg);
        fused_lif_trace<<<256, 256, 0, stream>>>(x, Wt, Lg, Cg, S_out, Uh, trace);
    } else {
        // C scratch reuses the trace region of d_out; trace_mfma runs last.
        double* C = (double*)trace;
        syn_current<<<T_STEPS * B_N, 256, 0, stream>>>(x, Wt, C);
        lif_pointwise<<<B_N * OUT_F / 256, 256, 0, stream>>>(C, S_out, Uh);
        trace_mfma<<<16 * B_N, 256, 0, stream>>>(x, Uh, trace);
    }
}

// Round 11
// 147.645 us; speedup vs baseline: 2.0125x; 2.0125x over previous
//
#include <hip/hip_runtime.h>

// Problem dims (hardcoded from reference)
#define T_STEPS 100
#define B_N     128
#define IN_F    512
#define OUT_F   512

// fp64 decay constants: exp(-DT/TAU_*)
#define ALPHA_D 0.8187307530779818   // exp(-1/5)   synaptic
#define BETA_D  0.9512294245007140   // exp(-1/20)  membrane

typedef __attribute__((ext_vector_type(8))) short bf16x8;
typedef __attribute__((ext_vector_type(4))) float f32x4;

static __device__ __forceinline__ unsigned int f2bf(float f) {
    union { float f; unsigned int u; } v; v.f = f;
    return (v.u + 0x7FFFu + ((v.u >> 16) & 1u)) >> 16;   // RNE
}

// ---------------------------------------------------------------------------
// K1: transpose W (OUT x IN) -> Wt (IN x OUT).  (ws[0 .. 1MB))
// ---------------------------------------------------------------------------
__global__ __launch_bounds__(256) void transposeW(const float* __restrict__ W,
                                                  float* __restrict__ Wt) {
    __shared__ float tile[32][33];
    const int bx = blockIdx.x & 15;   // i-tile
    const int by = blockIdx.x >> 4;   // o-tile
    const int tx = threadIdx.x & 31;
    const int ty = threadIdx.x >> 5;  // 0..7
#pragma unroll
    for (int k = 0; k < 32; k += 8) {
        int o = by * 32 + ty + k;
        tile[ty + k][tx] = W[o * IN_F + bx * 32 + tx];
    }
    __syncthreads();
#pragma unroll
    for (int k = 0; k < 32; k += 8) {
        int i = bx * 32 + ty + k;
        Wt[i * OUT_F + by * 32 + tx] = tile[tx][ty + k];
    }
}

// ---------------------------------------------------------------------------
// K2: fused grid (R6 pattern).
// Blocks [0, 512): pack x into bitmask Xbits[b][i] = 128 bits over t
//   (1 MB total -> L2-resident on every XCD regardless of write pressure).
// Blocks [512, 512+12800): synaptic current C[t,b,o] in fp64 via
//   ballot-compacted active list + uniform gather over L2-resident Wt.
// ---------------------------------------------------------------------------
__global__ __launch_bounds__(256) void syn_plus(const float* __restrict__ x,
                                                const float* __restrict__ Wt,
                                                double* __restrict__ C,
                                                unsigned int* __restrict__ Xbits) {
    const int tid = threadIdx.x;

    if ((int)blockIdx.x < 512) {
        // ---- x_to_bits: block covers (b, i-quarter of 128) ----
        const int b    = blockIdx.x >> 2;
        const int q    = blockIdx.x & 3;
        const int half = tid >> 7;            // 0: t<64 (words 0,1), 1: t>=64 (2,3)
        const int i    = q * 128 + (tid & 127);
        const float* xc = x + (size_t)b * IN_F + i;
        unsigned int wA = 0u, wB = 0u;
        if (half == 0) {
#pragma unroll
            for (int tt = 0; tt < 32; ++tt)
                wA |= (xc[(size_t)tt * (B_N * IN_F)] > 0.5f ? 1u : 0u) << tt;
#pragma unroll
            for (int tt = 0; tt < 32; ++tt)
                wB |= (xc[(size_t)(32 + tt) * (B_N * IN_F)] > 0.5f ? 1u : 0u) << tt;
        } else {
#pragma unroll
            for (int tt = 0; tt < 32; ++tt)
                wA |= (xc[(size_t)(64 + tt) * (B_N * IN_F)] > 0.5f ? 1u : 0u) << tt;
#pragma unroll
            for (int tt = 0; tt < 4; ++tt)    // t = 96..99; 100..127 stay 0
                wB |= (xc[(size_t)(96 + tt) * (B_N * IN_F)] > 0.5f ? 1u : 0u) << tt;
        }
        ((uint2*)Xbits)[(size_t)(b * IN_F + i) * 2 + half] = make_uint2(wA, wB);
        return;
    }

    // ---- syn_current ----
    const int tb = (int)blockIdx.x - 512;     // t*B + b

    __shared__ int s_idx[IN_F];
    __shared__ int s_cnt;

    if (tid < 64) {                      // wave 0 builds ascending active list
        const float* xr = x + (size_t)tb * IN_F;
        int base = 0;
#pragma unroll
        for (int j = 0; j < 8; ++j) {
            const float v = xr[j * 64 + tid];
            const unsigned long long m = __ballot(v > 0.5f);
            if (v > 0.5f) {
                const int pos = base + __popcll(m & ((1ull << tid) - 1ull));
                s_idx[pos] = j * 64 + tid;
            }
            base += __popcll(m);
        }
        if (tid == 0) s_cnt = base;
    }
    __syncthreads();

    const int cnt = s_cnt;
    double c0 = 0.0, c1 = 0.0;
    const float* W0 = Wt + tid;
    const float* W1 = Wt + tid + 256;
    for (int k = 0; k < cnt; ++k) {
        const int i = s_idx[k];          // LDS broadcast (uniform address)
        c0 += (double)W0[(size_t)i * OUT_F];
        c1 += (double)W1[(size_t)i * OUT_F];
    }

    double* Cr = C + (size_t)tb * OUT_F;
    Cr[tid]       = c0;
    Cr[tid + 256] = c1;
}

// ---------------------------------------------------------------------------
// K_B: elementwise LIF scan (R4-proven). fp64 recurrence, double-buffered
// 10-step chunks, static indices only.
// ---------------------------------------------------------------------------
#define LIF_STEP(BUF, J, CB)                                                   \
    {                                                                          \
        const int t = (CB) * 10 + (J);                                         \
        I = ALPHA_D * I + BUF[J];                                              \
        U = BETA_D * U + I;                                                    \
        const double Sv = (U >= 1.0) ? 1.0 : 0.0;                              \
        S_out[(size_t)t * N + pos] = (float)Sv;                                \
        Uh[(size_t)(2 * t) * N + pos] = (float)U;                              \
        U -= Sv;                                                               \
        Uh[(size_t)(2 * t + 1) * N + pos] = (float)U;                          \
        U -= Sv;                                                               \
    }

__global__ __launch_bounds__(256) void lif_pointwise(const double* __restrict__ C,
                                                     float* __restrict__ S_out,
                                                     float* __restrict__ Uh) {
    const int pos = blockIdx.x * 256 + threadIdx.x;   // b*OUT + o
    const size_t N = (size_t)B_N * OUT_F;

    double I = 0.0, U = 0.0;
    double bufA[10], bufB[10];

#pragma unroll
    for (int j = 0; j < 10; ++j) bufA[j] = C[(size_t)j * N + pos];

    for (int cb = 0; cb < 10; cb += 2) {
#pragma unroll
        for (int j = 0; j < 10; ++j) bufB[j] = C[((size_t)(cb + 1) * 10 + j) * N + pos];
#pragma unroll
        for (int j = 0; j < 10; ++j) LIF_STEP(bufA, j, cb)
        if (cb + 2 < 10) {
#pragma unroll
            for (int j = 0; j < 10; ++j) bufA[j] = C[((size_t)(cb + 2) * 10 + j) * N + pos];
        }
#pragma unroll
        for (int j = 0; j < 10; ++j) LIF_STEP(bufB, j, cb + 1)
    }
}

// ---------------------------------------------------------------------------
// K3: trace[b] = P^T @ X with a TINY, L2-immune read set.
// 1024 blocks (4/CU, 32 KB LDS), one per (b, 64-o panel).
// - P panel staged ONCE from U_post (26 MB total = compulsory), swizzled
//   bf16 LDS; A-fragments hoisted to registers.
// - Per i-tile: X tile expanded from the 1 MB bitmask (L2-resident) into
//   bf16 LDS (bit -> 0x3F80), ~50 VALU/thread; 16 MFMA; nt scalar stores.
// Per-block global reads = 34 KB. Kernel is write-stream dominated
// (134 MB nt stores), reads can't be thrashed by the writes.
// ---------------------------------------------------------------------------
__global__ __launch_bounds__(256) void trace_bits(const float* __restrict__ Uh,
                                                  const unsigned int* __restrict__ Xbits,
                                                  float* __restrict__ trace) {
    __shared__ char Psm[16384];   // [64 o][256B k] bf16 swz
    __shared__ char Xsm[16384];   // [64 i][256B k] bf16 swz

    const int tid = threadIdx.x;
    const int b   = blockIdx.x & 127;    // b%8 spreads XCDs
    const int ot  = blockIdx.x >> 7;     // 0..7 (64-o panel)

    // ---- stage P panel: 64 o x 128 k (t>=100 -> 0) ----
    {
        const int o_l = tid & 63;
        const int cg  = tid >> 6;        // 4 chunks per thread
        const float* up = Uh + (size_t)b * OUT_F + ot * 64 + o_l;
#pragma unroll
        for (int cc = 0; cc < 4; ++cc) {
            const int c = cg * 4 + cc;   // 16B chunk = 8 t
            unsigned int h[4];
#pragma unroll
            for (int jj = 0; jj < 4; ++jj) {
                unsigned int hw[2];
#pragma unroll
                for (int e = 0; e < 2; ++e) {
                    const int t = c * 8 + jj * 2 + e;
                    float p = 0.f;
                    if (t < T_STEPS) {
                        const float u  = up[(size_t)(2 * t + 1) * (B_N * OUT_F)];
                        const float du = fabsf(u - 1.0f);
                        const float dd = 1.0f + 0.03f * du;
                        p = __expf(-0.05f * (float)(T_STEPS - 1 - t)) / (dd * dd);
                    }
                    hw[e] = f2bf(p);
                }
                h[jj] = hw[0] | (hw[1] << 16);
            }
            const unsigned loff = (unsigned)(o_l * 256) +
                (((unsigned)(c * 16)) ^ (((unsigned)(o_l & 7)) << 4));
            *(uint4*)(Psm + loff) = make_uint4(h[0], h[1], h[2], h[3]);
        }
    }
    __syncthreads();

    // ---- hoist A-fragments (wave w owns o rows [w*16, w*16+16)) ----
    const int w = tid >> 6, l = tid & 63, lo16 = l & 15, g4 = l >> 4;
    bf16x8 af[4];
    {
        const int row = w * 16 + lo16;
#pragma unroll
        for (int kk = 0; kk < 4; ++kk) {
            const unsigned off = (unsigned)(row * 256 + kk * 64 + g4 * 16)
                                 ^ ((unsigned)(row & 7) << 4);
            af[kk] = *(const bf16x8*)(Psm + off);
        }
    }

    float* const tb = trace + (size_t)b * (OUT_F * IN_F) + (size_t)(ot * 64) * IN_F;
    const int i_l  = tid & 63;
    const int wsel = tid >> 6;           // which 32-bit word (k-range wsel*32..+31)

    for (int it = 0; it < 8; ++it) {
        __syncthreads();                 // Xsm free (prior MFMA reads done)

        // ---- expand X tile from bitmask: i = it*64 + i_l ----
        {
            const unsigned int word =
                Xbits[(size_t)(b * IN_F + it * 64 + i_l) * 4 + wsel];
#pragma unroll
            for (int j = 0; j < 4; ++j) {    // chunk c = wsel*4+j covers bits j*8..j*8+7
                unsigned int h[4];
#pragma unroll
                for (int m = 0; m < 4; ++m) {
                    const unsigned b0 = (word >> (j * 8 + 2 * m)) & 1u;
                    const unsigned b1 = (word >> (j * 8 + 2 * m + 1)) & 1u;
                    h[m] = b0 * 0x3F80u | b1 * 0x3F800000u;   // bf16(1.0) pair
                }
                const int c = wsel * 4 + j;
                const unsigned loff = (unsigned)(i_l * 256) +
                    (((unsigned)(c * 16)) ^ (((unsigned)(i_l & 7)) << 4));
                *(uint4*)(Xsm + loff) = make_uint4(h[0], h[1], h[2], h[3]);
            }
        }
        __syncthreads();

        // ---- MFMA: 64(o) x 64(i) per block quadrant per wave row-slice ----
        f32x4 acc[4];
#pragma unroll
        for (int n = 0; n < 4; ++n) acc[n] = (f32x4){0.f, 0.f, 0.f, 0.f};

#pragma unroll
        for (int kk = 0; kk < 4; ++kk) {
            bf16x8 bfr[4];
#pragma unroll
            for (int n = 0; n < 4; ++n) {
                const int row = n * 16 + lo16;
                const unsigned off = (unsigned)(row * 256 + kk * 64 + g4 * 16)
                                     ^ ((unsigned)(row & 7) << 4);
                bfr[n] = *(const bf16x8*)(Xsm + off);
            }
#pragma unroll
            for (int n = 0; n < 4; ++n)
                acc[n] = __builtin_amdgcn_mfma_f32_16x16x32_bf16(af[kk], bfr[n], acc[n], 0, 0, 0);
        }

        // ---- store; D: col=lane&15 (i), row=(lane>>4)*4+reg (o) ----
#pragma unroll
        for (int rr = 0; rr < 4; ++rr) {
            const int o = w * 16 + g4 * 4 + rr;
#pragma unroll
            for (int n = 0; n < 4; ++n)
                __builtin_nontemporal_store(acc[n][rr],
                    tb + (size_t)o * IN_F + it * 64 + n * 16 + lo16);
        }
    }
}

// ---------------------------------------------------------------------------
extern "C" void kernel_launch(void* const* d_in, const int* in_sizes, int n_in,
                              void* d_out, int out_size, void* d_ws, size_t ws_size,
                              hipStream_t stream) {
    const float* x = (const float*)d_in[0];   // (T, B, IN) binary spikes
    const float* W = (const float*)d_in[1];   // (OUT, IN)

    float* out   = (float*)d_out;
    float* S_out = out;                                            // (T, B, OUT)
    float* Uh    = out + (size_t)T_STEPS * B_N * OUT_F;            // (2T, B, OUT)
    float* trace = Uh + (size_t)2 * T_STEPS * B_N * OUT_F;         // (B, OUT, IN)

    // ws layout: Wt (1 MB) | Xbits (1 MB). ws >= 3.2 MB proven (R9/R10 ran).
    float*        Wt    = (float*)d_ws;
    unsigned int* Xbits = (unsigned int*)((char*)d_ws + (size_t)IN_F * OUT_F * 4);

    // C (f64, 52 MB) reuses the trace region of d_out; trace_bits reads only
    // Uh + Xbits and runs last, so no hazard.
    double* C = (double*)trace;

    transposeW<<<256, 256, 0, stream>>>(W, Wt);
    syn_plus<<<512 + T_STEPS * B_N, 256, 0, stream>>>(x, Wt, C, Xbits);
    lif_pointwise<<<B_N * OUT_F / 256, 256, 0, stream>>>(C, S_out, Uh);
    trace_bits<<<1024, 256, 0, stream>>>(Uh, Xbits, trace);
}

// Round 12
// 135.429 us; speedup vs baseline: 2.1940x; 1.0902x over previous
//
#include <hip/hip_runtime.h>

// Problem dims (hardcoded from reference)
#define T_STEPS 100
#define B_N     128
#define IN_F    512
#define OUT_F   512

// fp64 decay constants: exp(-DT/TAU_*)
#define ALPHA_D 0.8187307530779818   // exp(-1/5)   synaptic
#define BETA_D  0.9512294245007140   // exp(-1/20)  membrane

typedef __attribute__((ext_vector_type(8))) short bf16x8;
typedef __attribute__((ext_vector_type(4))) float f32x4;

static __device__ __forceinline__ unsigned int f2bf(float f) {
    union { float f; unsigned int u; } v; v.f = f;
    return (v.u + 0x7FFFu + ((v.u >> 16) & 1u)) >> 16;   // RNE
}

// expand 8 binary bits -> 8 bf16 (1.0 / 0.0), packed 2-per-u32
static __device__ __forceinline__ bf16x8 expand8(unsigned int byte) {
    union { unsigned int u[4]; bf16x8 v; } r;
#pragma unroll
    for (int p = 0; p < 4; ++p) {
        r.u[p] = (((byte >> (2 * p)) & 1u) ? 0x3F80u : 0u) |
                 (((byte >> (2 * p + 1)) & 1u) ? 0x3F800000u : 0u);
    }
    return r.v;
}

// ---------------------------------------------------------------------------
// K1: transpose W (OUT x IN) -> Wt (IN x OUT).  (ws[0 .. 1MB))
// ---------------------------------------------------------------------------
__global__ __launch_bounds__(256) void transposeW(const float* __restrict__ W,
                                                  float* __restrict__ Wt) {
    __shared__ float tile[32][33];
    const int bx = blockIdx.x & 15;   // i-tile
    const int by = blockIdx.x >> 4;   // o-tile
    const int tx = threadIdx.x & 31;
    const int ty = threadIdx.x >> 5;  // 0..7
#pragma unroll
    for (int k = 0; k < 32; k += 8) {
        int o = by * 32 + ty + k;
        tile[ty + k][tx] = W[o * IN_F + bx * 32 + tx];
    }
    __syncthreads();
#pragma unroll
    for (int k = 0; k < 32; k += 8) {
        int i = bx * 32 + ty + k;
        Wt[i * OUT_F + by * 32 + tx] = tile[tx][ty + k];
    }
}

// ---------------------------------------------------------------------------
// K2: fused grid.
// Blocks [0, 512): pack x into bitmask Xbits[b][i] = 128 bits over t (1 MB).
// Blocks [512, 512+12800): synaptic current C[t,b,o] in fp64 via
//   ballot-compacted active list + uniform gather over L2-resident Wt.
// ---------------------------------------------------------------------------
__global__ __launch_bounds__(256) void syn_plus(const float* __restrict__ x,
                                                const float* __restrict__ Wt,
                                                double* __restrict__ C,
                                                unsigned int* __restrict__ Xbits) {
    const int tid = threadIdx.x;

    if ((int)blockIdx.x < 512) {
        // ---- x_to_bits: block covers (b, i-quarter of 128) ----
        const int b    = blockIdx.x >> 2;
        const int q    = blockIdx.x & 3;
        const int half = tid >> 7;            // 0: t<64 (words 0,1), 1: t>=64 (2,3)
        const int i    = q * 128 + (tid & 127);
        const float* xc = x + (size_t)b * IN_F + i;
        unsigned int wA = 0u, wB = 0u;
        if (half == 0) {
#pragma unroll
            for (int tt = 0; tt < 32; ++tt)
                wA |= (xc[(size_t)tt * (B_N * IN_F)] > 0.5f ? 1u : 0u) << tt;
#pragma unroll
            for (int tt = 0; tt < 32; ++tt)
                wB |= (xc[(size_t)(32 + tt) * (B_N * IN_F)] > 0.5f ? 1u : 0u) << tt;
        } else {
#pragma unroll
            for (int tt = 0; tt < 32; ++tt)
                wA |= (xc[(size_t)(64 + tt) * (B_N * IN_F)] > 0.5f ? 1u : 0u) << tt;
#pragma unroll
            for (int tt = 0; tt < 4; ++tt)    // t = 96..99; 100..127 stay 0
                wB |= (xc[(size_t)(96 + tt) * (B_N * IN_F)] > 0.5f ? 1u : 0u) << tt;
        }
        ((uint2*)Xbits)[(size_t)(b * IN_F + i) * 2 + half] = make_uint2(wA, wB);
        return;
    }

    // ---- syn_current ----
    const int tb = (int)blockIdx.x - 512;     // t*B + b

    __shared__ int s_idx[IN_F];
    __shared__ int s_cnt;

    if (tid < 64) {                      // wave 0 builds ascending active list
        const float* xr = x + (size_t)tb * IN_F;
        int base = 0;
#pragma unroll
        for (int j = 0; j < 8; ++j) {
            const float v = xr[j * 64 + tid];
            const unsigned long long m = __ballot(v > 0.5f);
            if (v > 0.5f) {
                const int pos = base + __popcll(m & ((1ull << tid) - 1ull));
                s_idx[pos] = j * 64 + tid;
            }
            base += __popcll(m);
        }
        if (tid == 0) s_cnt = base;
    }
    __syncthreads();

    const int cnt = s_cnt;
    double c0 = 0.0, c1 = 0.0;
    const float* W0 = Wt + tid;
    const float* W1 = Wt + tid + 256;
    for (int k = 0; k < cnt; ++k) {
        const int i = s_idx[k];          // LDS broadcast (uniform address)
        c0 += (double)W0[(size_t)i * OUT_F];
        c1 += (double)W1[(size_t)i * OUT_F];
    }

    double* Cr = C + (size_t)tb * OUT_F;
    Cr[tid]       = c0;
    Cr[tid + 256] = c1;
}

// ---------------------------------------------------------------------------
// K_B: elementwise LIF scan (R4-proven). fp64 recurrence, double-buffered
// 10-step chunks, static indices only.
// ---------------------------------------------------------------------------
#define LIF_STEP(BUF, J, CB)                                                   \
    {                                                                          \
        const int t = (CB) * 10 + (J);                                         \
        I = ALPHA_D * I + BUF[J];                                              \
        U = BETA_D * U + I;                                                    \
        const double Sv = (U >= 1.0) ? 1.0 : 0.0;                              \
        S_out[(size_t)t * N + pos] = (float)Sv;                                \
        Uh[(size_t)(2 * t) * N + pos] = (float)U;                              \
        U -= Sv;                                                               \
        Uh[(size_t)(2 * t + 1) * N + pos] = (float)U;                          \
        U -= Sv;                                                               \
    }

__global__ __launch_bounds__(256) void lif_pointwise(const double* __restrict__ C,
                                                     float* __restrict__ S_out,
                                                     float* __restrict__ Uh) {
    const int pos = blockIdx.x * 256 + threadIdx.x;   // b*OUT + o
    const size_t N = (size_t)B_N * OUT_F;

    double I = 0.0, U = 0.0;
    double bufA[10], bufB[10];

#pragma unroll
    for (int j = 0; j < 10; ++j) bufA[j] = C[(size_t)j * N + pos];

    for (int cb = 0; cb < 10; cb += 2) {
#pragma unroll
        for (int j = 0; j < 10; ++j) bufB[j] = C[((size_t)(cb + 1) * 10 + j) * N + pos];
#pragma unroll
        for (int j = 0; j < 10; ++j) LIF_STEP(bufA, j, cb)
        if (cb + 2 < 10) {
#pragma unroll
            for (int j = 0; j < 10; ++j) bufA[j] = C[((size_t)(cb + 2) * 10 + j) * N + pos];
        }
#pragma unroll
        for (int j = 0; j < 10; ++j) LIF_STEP(bufB, j, cb + 1)
    }
}

// ---------------------------------------------------------------------------
// K3: trace[b] = P^T @ X; X fabricated IN REGISTERS from the 1 MB bitmask.
// 1024 blocks (b, 64-o panel). P staged once in 16 KB LDS, frags hoisted;
// main loop is barrier-free: per i-tile {4 uint4 L2 loads, ~300 VALU bit->
// bf16 selects, 16 MFMA, 16 nt stores}. Correctness: lane l's B-fragment
// element j must equal X[i=n*16+(l&15)][k=kk*32+(l>>4)*8+j] — exactly bits
// (g4*8..+7) of Xbits word kk — matching the [feat][k] map used for A(P),
// so the shared-k-permutation invariance argument still holds.
// ---------------------------------------------------------------------------
__global__ __launch_bounds__(256) void trace_bits2(const float* __restrict__ Uh,
                                                   const unsigned int* __restrict__ Xbits,
                                                   float* __restrict__ trace) {
    __shared__ char Psm[16384];   // [64 o][256B k] bf16 swz

    const int tid = threadIdx.x;
    const int b   = blockIdx.x & 127;    // b%8 spreads XCDs
    const int ot  = blockIdx.x >> 7;     // 0..7 (64-o panel)

    // ---- stage P panel: 64 o x 128 k (t>=100 -> 0) ----
    {
        const int o_l = tid & 63;
        const int cg  = tid >> 6;        // 4 chunks per thread
        const float* up = Uh + (size_t)b * OUT_F + ot * 64 + o_l;
#pragma unroll
        for (int cc = 0; cc < 4; ++cc) {
            const int c = cg * 4 + cc;   // 16B chunk = 8 t
            unsigned int h[4];
#pragma unroll
            for (int jj = 0; jj < 4; ++jj) {
                unsigned int hw[2];
#pragma unroll
                for (int e = 0; e < 2; ++e) {
                    const int t = c * 8 + jj * 2 + e;
                    float p = 0.f;
                    if (t < T_STEPS) {
                        const float u  = up[(size_t)(2 * t + 1) * (B_N * OUT_F)];
                        const float du = fabsf(u - 1.0f);
                        const float dd = 1.0f + 0.03f * du;
                        p = __expf(-0.05f * (float)(T_STEPS - 1 - t)) / (dd * dd);
                    }
                    hw[e] = f2bf(p);
                }
                h[jj] = hw[0] | (hw[1] << 16);
            }
            const unsigned loff = (unsigned)(o_l * 256) +
                (((unsigned)(c * 16)) ^ (((unsigned)(o_l & 7)) << 4));
            *(uint4*)(Psm + loff) = make_uint4(h[0], h[1], h[2], h[3]);
        }
    }
    __syncthreads();

    // ---- hoist A-fragments (wave w owns o rows [w*16, w*16+16)) ----
    const int w = tid >> 6, l = tid & 63, lo16 = l & 15, g4 = l >> 4;
    bf16x8 af[4];
    {
        const int row = w * 16 + lo16;
#pragma unroll
        for (int kk = 0; kk < 4; ++kk) {
            const unsigned off = (unsigned)(row * 256 + kk * 64 + g4 * 16)
                                 ^ ((unsigned)(row & 7) << 4);
            af[kk] = *(const bf16x8*)(Psm + off);
        }
    }

    float* const tb = trace + (size_t)b * (OUT_F * IN_F) + (size_t)(ot * 64) * IN_F;
    const uint4* const xb = (const uint4*)Xbits + (size_t)b * IN_F;  // one uint4 / i
    const int sh = g4 * 8;

    for (int it = 0; it < 8; ++it) {
        // bit-words for this lane's 4 B-columns (i = it*64 + n*16 + lo16)
        uint4 xw[4];
#pragma unroll
        for (int n = 0; n < 4; ++n) xw[n] = xb[it * 64 + n * 16 + lo16];

        f32x4 acc[4];
#pragma unroll
        for (int n = 0; n < 4; ++n) acc[n] = (f32x4){0.f, 0.f, 0.f, 0.f};

#pragma unroll
        for (int kk = 0; kk < 4; ++kk) {
#pragma unroll
            for (int n = 0; n < 4; ++n) {
                const unsigned int word = ((const unsigned int*)&xw[n])[kk];
                const bf16x8 bfr = expand8((word >> sh) & 0xFFu);
                acc[n] = __builtin_amdgcn_mfma_f32_16x16x32_bf16(af[kk], bfr, acc[n], 0, 0, 0);
            }
        }

        // ---- store; D: col=lane&15 (i), row=(lane>>4)*4+reg (o) ----
#pragma unroll
        for (int rr = 0; rr < 4; ++rr) {
            const int o = w * 16 + g4 * 4 + rr;
#pragma unroll
            for (int n = 0; n < 4; ++n)
                __builtin_nontemporal_store(acc[n][rr],
                    tb + (size_t)o * IN_F + it * 64 + n * 16 + lo16);
        }
    }
}

// ---------------------------------------------------------------------------
extern "C" void kernel_launch(void* const* d_in, const int* in_sizes, int n_in,
                              void* d_out, int out_size, void* d_ws, size_t ws_size,
                              hipStream_t stream) {
    const float* x = (const float*)d_in[0];   // (T, B, IN) binary spikes
    const float* W = (const float*)d_in[1];   // (OUT, IN)

    float* out   = (float*)d_out;
    float* S_out = out;                                            // (T, B, OUT)
    float* Uh    = out + (size_t)T_STEPS * B_N * OUT_F;            // (2T, B, OUT)
    float* trace = Uh + (size_t)2 * T_STEPS * B_N * OUT_F;         // (B, OUT, IN)

    // ws layout: Wt (1 MB) | Xbits (1 MB). ws >= 3.2 MB proven (R9/R10 ran).
    float*        Wt    = (float*)d_ws;
    unsigned int* Xbits = (unsigned int*)((char*)d_ws + (size_t)IN_F * OUT_F * 4);

    // C (f64, 52 MB) reuses the trace region of d_out; trace_bits2 reads only
    // Uh + Xbits and runs last, so no hazard.
    double* C = (double*)trace;

    transposeW<<<256, 256, 0, stream>>>(W, Wt);
    syn_plus<<<512 + T_STEPS * B_N, 256, 0, stream>>>(x, Wt, C, Xbits);
    lif_pointwise<<<B_N * OUT_F / 256, 256, 0, stream>>>(C, S_out, Uh);
    trace_bits2<<<1024, 256, 0, stream>>>(Uh, Xbits, trace);
}